// Round 1
// baseline (468.200 us; speedup 1.0000x reference)
//
#include <hip/hip_runtime.h>

// Problem constants (match reference)
#define NB 8
#define NC 32
#define NL 32768
#define NK 11
#define DIL 10
#define PADS 50   // ceil(DIL*(NK-1)/2)
#define PADO 5    // (NK-1)/2
#define EPSV 1e-3f

// ---------------- BN + ReLU (vectorized float4) ----------------
__global__ __launch_bounds__(256) void bn_relu_k(
    const float* __restrict__ x, const float* __restrict__ gamma,
    const float* __restrict__ beta, const float* __restrict__ mean,
    const float* __restrict__ var, float* __restrict__ out)
{
    long idx = (long)blockIdx.x * blockDim.x + threadIdx.x;
    long i4 = idx * 4;
    if (i4 >= (long)NB * NC * NL) return;
    int c = (int)((i4 / NL) % NC);
    float sc = gamma[c] * rsqrtf(var[c] + EPSV);
    float sh = beta[c] - mean[c] * sc;
    float4 v = *reinterpret_cast<const float4*>(x + i4);
    float4 r;
    r.x = fmaxf(fmaf(v.x, sc, sh), 0.f);
    r.y = fmaxf(fmaf(v.y, sc, sh), 0.f);
    r.z = fmaxf(fmaf(v.z, sc, sh), 0.f);
    r.w = fmaxf(fmaf(v.w, sc, sh), 0.f);
    *reinterpret_cast<float4*>(out + i4) = r;
}

// ---------------- Weight transposes (tiny, once per launch) ----------------
// deform weight [CO][CI][K] -> [K][CI][CO]  (inner index contiguous+uniform)
__global__ void tw_deform_k(const float* __restrict__ w, float* __restrict__ wt)
{
    int i = blockIdx.x * blockDim.x + threadIdx.x;
    if (i >= NC * NC * NK) return;
    int co  = i / (NC * NK);
    int rem = i % (NC * NK);
    int ci  = rem / NK;
    int k   = rem % NK;
    wt[(k * NC + ci) * NC + co] = w[i];
}

// offset weight [KO][CI][KK] -> [CI][KK][KO]
__global__ void tw_off_k(const float* __restrict__ w, float* __restrict__ wt)
{
    int i = blockIdx.x * blockDim.x + threadIdx.x;
    if (i >= NK * NC * NK) return;
    int ko  = i / (NC * NK);
    int rem = i % (NC * NK);
    int ci  = rem / NK;
    int kk  = rem % NK;
    wt[(ci * NK + kk) * NK + ko] = w[i];
}

// ---------------- Offset-predicting conv1d ('same', pad=5) ----------------
// act: [B][C][L], wt: [CI][KK][KO], out off: [B][KO][L]
__global__ __launch_bounds__(256) void off_conv_k(
    const float* __restrict__ act, const float* __restrict__ wt,
    const float* __restrict__ bias, float* __restrict__ off)
{
    int t = blockIdx.x * blockDim.x + threadIdx.x;   // over B*L
    int b = t >> 15;            // / NL
    int l = t & (NL - 1);       // % NL
    const float* ab = act + (long)b * NC * NL;

    float acc[NK];
    #pragma unroll
    for (int ko = 0; ko < NK; ++ko) acc[ko] = bias[ko];

    for (int c = 0; c < NC; ++c) {
        const float* ac = ab + c * NL;
        float v[NK];
        #pragma unroll
        for (int kk = 0; kk < NK; ++kk) {
            int p = l + kk - PADO;
            float m = (p >= 0 && p < NL) ? 1.f : 0.f;
            p = min(max(p, 0), NL - 1);
            v[kk] = ac[p] * m;
        }
        const float* wc = wt + c * NK * NK;   // uniform address -> s_loads
        #pragma unroll
        for (int kk = 0; kk < NK; ++kk) {
            #pragma unroll
            for (int ko = 0; ko < NK; ++ko)
                acc[ko] = fmaf(v[kk], wc[kk * NK + ko], acc[ko]);
        }
    }
    #pragma unroll
    for (int ko = 0; ko < NK; ++ko)
        off[((long)b * NK + ko) * NL + l] = acc[ko];
}

// ---------------- Deformable conv1d ----------------
// act: [B][C][L], off: [B][K][L], wt: [K][CI][CO]
// MODE 0: out = relu(bn2(y))   (fused BN2+ReLU epilogue)
// MODE 1: out = y + resid      (fused residual epilogue)
template <int MODE>
__global__ __launch_bounds__(256) void deform_k(
    const float* __restrict__ act, const float* __restrict__ off,
    const float* __restrict__ wt, const float* __restrict__ bias,
    const float* __restrict__ g, const float* __restrict__ be,
    const float* __restrict__ mn, const float* __restrict__ vr,
    const float* __restrict__ resid, float* __restrict__ out)
{
    int t = blockIdx.x * blockDim.x + threadIdx.x;   // over B*L
    int b = t >> 15;
    int l = t & (NL - 1);
    const float* ab = act + (long)b * NC * NL;

    float acc[NC];
    #pragma unroll
    for (int co = 0; co < NC; ++co) acc[co] = 0.f;

    #pragma unroll 1
    for (int k = 0; k < NK; ++k) {
        float o   = off[((long)b * NK + k) * NL + l];
        float pos = (float)(l + k * DIL - PADS) + o;
        float lof = floorf(pos);
        float fr  = pos - lof;
        int lo = (int)lof;
        int hi = lo + 1;
        float ma = (lo >= 0 && lo < NL) ? 1.f : 0.f;
        float mb = (hi >= 0 && hi < NL) ? 1.f : 0.f;
        int ia = min(max(lo, 0), NL - 1);
        int ib = min(max(hi, 0), NL - 1);
        const float* wk = wt + k * NC * NC;

        #pragma unroll 4
        for (int c = 0; c < NC; ++c) {
            float a0 = ab[c * NL + ia] * ma;
            float a1 = ab[c * NL + ib] * mb;
            float s  = fmaf(a1 - a0, fr, a0);   // lerp
            const float* wc = wk + c * NC;      // uniform+contiguous -> s_load_dwordx16
            #pragma unroll
            for (int co = 0; co < NC; ++co)
                acc[co] = fmaf(s, wc[co], acc[co]);
        }
    }

    long obase = (long)b * NC * NL + l;
    if (MODE == 0) {
        #pragma unroll
        for (int co = 0; co < NC; ++co) {
            float sc = g[co] * rsqrtf(vr[co] + EPSV);
            float sh = be[co] - mn[co] * sc;
            float y  = fmaxf(fmaf(acc[co] + bias[co], sc, sh), 0.f);
            out[obase + (long)co * NL] = y;
        }
    } else {
        #pragma unroll
        for (int co = 0; co < NC; ++co) {
            long oi = obase + (long)co * NL;
            out[oi] = acc[co] + bias[co] + resid[oi];
        }
    }
}

extern "C" void kernel_launch(void* const* d_in, const int* in_sizes, int n_in,
                              void* d_out, int out_size, void* d_ws, size_t ws_size,
                              hipStream_t stream)
{
    const float* x      = (const float*)d_in[0];
    const float* bn1_g  = (const float*)d_in[1];
    const float* bn1_b  = (const float*)d_in[2];
    const float* bn1_m  = (const float*)d_in[3];
    const float* bn1_v  = (const float*)d_in[4];
    const float* bn2_g  = (const float*)d_in[5];
    const float* bn2_b  = (const float*)d_in[6];
    const float* bn2_m  = (const float*)d_in[7];
    const float* bn2_v  = (const float*)d_in[8];
    const float* off1_w = (const float*)d_in[9];
    const float* off1_b = (const float*)d_in[10];
    const float* off2_w = (const float*)d_in[11];
    const float* off2_b = (const float*)d_in[12];
    const float* dc1_w  = (const float*)d_in[13];
    const float* dc1_b  = (const float*)d_in[14];
    const float* dc2_w  = (const float*)d_in[15];
    const float* dc2_b  = (const float*)d_in[16];
    float* out = (float*)d_out;

    // Workspace layout (~43.1 MB):
    //   act2   : NB*NC*NL floats            = 32 MiB
    //   offb   : NB*NK*NL floats            = 11 MiB
    //   wt1,wt2: NC*NC*NK floats each       = 44 KiB each
    //   wto1/2 : NC*NK*NK floats each       = 15 KiB each
    char* ws = (char*)d_ws;
    float* act2 = (float*)ws;
    float* offb = (float*)(ws + (size_t)NB * NC * NL * 4);
    float* wt1  = (float*)(ws + (size_t)NB * NC * NL * 4 + (size_t)NB * NK * NL * 4);
    float* wt2  = wt1 + NC * NC * NK;
    float* wto1 = wt2 + NC * NC * NK;
    float* wto2 = wto1 + NC * NK * NK;

    // act1 lives in d_out (free scratch; fully overwritten by the last kernel)
    float* act1 = out;

    // Tiny weight-transpose preps
    tw_deform_k<<<(NC * NC * NK + 255) / 256, 256, 0, stream>>>(dc1_w, wt1);
    tw_deform_k<<<(NC * NC * NK + 255) / 256, 256, 0, stream>>>(dc2_w, wt2);
    tw_off_k<<<(NK * NC * NK + 255) / 256, 256, 0, stream>>>(off1_w, wto1);
    tw_off_k<<<(NK * NC * NK + 255) / 256, 256, 0, stream>>>(off2_w, wto2);

    const int total4 = NB * NC * NL / 4;           // 2,097,152
    bn_relu_k<<<total4 / 256, 256, 0, stream>>>(x, bn1_g, bn1_b, bn1_m, bn1_v, act1);

    const int grid_bl = NB * NL / 256;             // 1024
    off_conv_k<<<grid_bl, 256, 0, stream>>>(act1, wto1, off1_b, offb);
    deform_k<0><<<grid_bl, 256, 0, stream>>>(act1, offb, wt1, dc1_b,
                                             bn2_g, bn2_b, bn2_m, bn2_v,
                                             nullptr, act2);
    off_conv_k<<<grid_bl, 256, 0, stream>>>(act2, wto2, off2_b, offb);
    deform_k<1><<<grid_bl, 256, 0, stream>>>(act2, offb, wt2, dc2_b,
                                             nullptr, nullptr, nullptr, nullptr,
                                             x, out);
}